// Round 16
// baseline (34.666 us; speedup 1.0000x reference)
//
#include <hip/hip_runtime.h>
#include <math.h>

// x: [32,3,512,512] f32.
// Stage 1 = r9/r15 structure (best measured ~26.5us) + FAST/SAFE template
// split + split accumulators. Register-only row sweep, 8 cols/lane
// (2 aligned float4 loads/row; wave spans 512 cols), Sobel via rolling
// vertical pair-sums, 4 shuffles/mag row + 2/pool row, builtin v_sqrt_f32,
// 12 output rows/wave, 44 chunks/(b,c) (43 real + 1 dummy), 4224 waves.
// FAST path (chunks 1..41): rows 10..505 -> no row-bound compares, no
// rmask multiplies, no output-row checks (~140 VALU/wave removed).
// SAFE path (chunks 0/42/43): r15's guarded logic verbatim.
// Split accumulators s0/s1, ss0/ss1 break the 8-deep add chain into 2x4.
// Stage 2: 32 blocks (one per b); waves 0-2 reduce each channel's 44
// double2 partials lane-parallel, then 6->32(relu)->64 MLP.
// Grid: (11, 96) x 256  +  (32) x 256.

template <bool SAFE>
__device__ __forceinline__ void sweep12(const float* __restrict__ xb,
                                        int row0, int lane,
                                        float& s_out, float& ss_out) {
  auto load8 = [&](int r, float* o) {
    if (SAFE && (unsigned)r >= 512u) {       // folds away in FAST
#pragma unroll
      for (int k = 0; k < 8; ++k) o[k] = 0.f;
      return;
    }
    const float* p = xb + (size_t)r * 512;
    float4 u = *(const float4*)(p);
    float4 v = *(const float4*)(p + 4);
    o[0] = u.x; o[1] = u.y; o[2] = u.z; o[3] = u.w;
    o[4] = v.x; o[5] = v.y; o[6] = v.z; o[7] = v.w;
  };

  float S[8], X[8];
  {
    float t0[8], t1[8];
    load8(row0 - 2, t0);
    load8(row0 - 1, t1);
#pragma unroll
    for (int k = 0; k < 8; ++k) { S[k] = t0[k] + t1[k]; X[k] = t1[k]; }
  }

  // Emit mag row rm (consumes x[rm+1]); advances S,X. mg=0 if rm OOB (SAFE).
  auto magstep = [&](int rm, float* mg) {
    float xn[8], S2[8], a[8], b[8];
    load8(rm + 1, xn);
#pragma unroll
    for (int k = 0; k < 8; ++k) S2[k] = X[k] + xn[k];
#pragma unroll
    for (int k = 0; k < 8; ++k) { a[k] = S[k] + S2[k]; b[k] = S[k] - S2[k]; }
    float aL = __shfl_up(a[7], 1), aR = __shfl_down(a[0], 1);
    float bL = __shfl_up(b[7], 1), bR = __shfl_down(b[0], 1);
    if (lane == 0)  { aL = 0.f; bL = 0.f; }   // image col -1 = 0
    if (lane == 63) { aR = 0.f; bR = 0.f; }   // image col 512 = 0
#pragma unroll
    for (int j = 0; j < 8; ++j) {
      float am = j ? a[j - 1] : aL;
      float ap = (j < 7) ? a[j + 1] : aR;
      float bm = j ? b[j - 1] : bL;
      float bp = (j < 7) ? b[j + 1] : bR;
      float gx = am - ap;                      // horiz [1,0,-1]
      float gy = fmaf(2.f, b[j], bm + bp);     // horiz [1,2,1]
      float m2 = fmaf(gx, gx, 1e-6f);
      m2 = fmaf(gy, gy, m2);
      mg[j] = __builtin_amdgcn_sqrtf(m2);
    }
    if (SAFE) {
      const float rmask = ((unsigned)rm < 512u) ? 1.f : 0.f;
#pragma unroll
      for (int j = 0; j < 8; ++j) mg[j] *= rmask;
    }
#pragma unroll
    for (int k = 0; k < 8; ++k) { S[k] = S2[k]; X[k] = xn[k]; }
  };

  float MM[8], MC[8], MP[8];
  magstep(row0 - 1, MM);
  magstep(row0, MC);

  float s0 = 0.f, s1 = 0.f, ss0 = 0.f, ss1 = 0.f;
#pragma unroll
  for (int i = 0; i < 12; ++i) {
    magstep(row0 + 1 + i, MP);               // mag[r+1]
    if (!SAFE || (unsigned)(row0 + i) < 512u) {  // wave-uniform; folds in FAST
      float cs[8];
#pragma unroll
      for (int k = 0; k < 8; ++k) cs[k] = (MM[k] + MP[k]) + MC[k];
      float csL = __shfl_up(cs[7], 1), csR = __shfl_down(cs[0], 1);
      if (lane == 0) csL = 0.f;
      if (lane == 63) csR = 0.f;
#pragma unroll
      for (int j = 0; j < 8; ++j) {
        float cm = j ? cs[j - 1] : csL;
        float cp = (j < 7) ? cs[j + 1] : csR;
        float t = (cm + cp) + cs[j];
        if (j & 1) { s1 += t; ss1 = fmaf(t, t, ss1); }
        else       { s0 += t; ss0 = fmaf(t, t, ss0); }
      }
    }
#pragma unroll
    for (int k = 0; k < 8; ++k) { MM[k] = MC[k]; MC[k] = MP[k]; }
  }
  s_out = s0 + s1;
  ss_out = ss0 + ss1;
}

__global__ __launch_bounds__(256) void sobel_pool_stats(
    const float* __restrict__ x, double* __restrict__ parts) {
  const int tid = threadIdx.x;
  const int lane = tid & 63;
  const int w = tid >> 6;
  const int bc = blockIdx.y;                 // 0..95
  const int chunk = blockIdx.x * 4 + w;      // 0..43 (43 = dummy)
  const int row0 = chunk * 12;
  const float* __restrict__ xb = x + (size_t)bc * (512 * 512) + lane * 8;

  float s, ss;
  if (chunk >= 1 && chunk <= 41) sweep12<false>(xb, row0, lane, s, ss);
  else                           sweep12<true>(xb, row0, lane, s, ss);

  // per-wave double reduction; fold deferred /9, /81
  double ds = (double)s * (1.0 / 9.0);
  double dss = (double)ss * (1.0 / 81.0);
  for (int off = 32; off > 0; off >>= 1) {
    ds += __shfl_down(ds, off);
    dss += __shfl_down(dss, off);
  }
  if (lane == 0) {
    size_t idx = ((size_t)bc * 44 + chunk) * 2;
    parts[idx] = ds;
    parts[idx + 1] = dss;
  }
}

// One block per batch image b: waves 0-2 reduce channel 0-2's 44 double2
// partials lane-parallel, then feats [m0,s0,m1,s1,m2,s2] -> MLP -> out.
__global__ __launch_bounds__(256) void stats_mlp(
    const double* __restrict__ parts,
    const float* __restrict__ w1, const float* __restrict__ b1,
    const float* __restrict__ w2, const float* __restrict__ b2,
    float* __restrict__ out) {
  __shared__ float feats[6];
  __shared__ float hbuf[32];
  const int tid = threadIdx.x;
  const int lane = tid & 63;
  const int w = tid >> 6;
  const int b = blockIdx.x;                  // 0..31

  if (w < 3) {
    const int bc = b * 3 + w;
    const double2* p2 = (const double2*)(parts + (size_t)bc * 88);
    double s = 0.0, ss = 0.0;
    if (lane < 44) {
      double2 v = p2[lane];
      s = v.x;
      ss = v.y;
    }
    for (int off = 32; off > 0; off >>= 1) {
      s += __shfl_down(s, off);
      ss += __shfl_down(ss, off);
    }
    if (lane == 0) {
      const double N = 262144.0;
      double mean = s / N;
      double var = (ss - s * s / N) / (N - 1.0);
      if (var < 0.0) var = 0.0;
      feats[2 * w] = (float)mean;
      feats[2 * w + 1] = (float)sqrt(var);
    }
  }
  __syncthreads();

  if (tid < 32) {
    float acc = b1[tid];
#pragma unroll
    for (int k = 0; k < 6; ++k) acc += feats[k] * w1[tid * 6 + k];
    hbuf[tid] = acc > 0.f ? acc : 0.f;
  }
  __syncthreads();

  if (tid < 64) {
    float acc = b2[tid];
#pragma unroll
    for (int j = 0; j < 32; ++j) acc += hbuf[j] * w2[tid * 32 + j];
    out[(size_t)b * 64 + tid] = acc;
  }
}

extern "C" void kernel_launch(void* const* d_in, const int* in_sizes, int n_in,
                              void* d_out, int out_size, void* d_ws, size_t ws_size,
                              hipStream_t stream) {
  const float* x = (const float*)d_in[0];
  const float* w1 = (const float*)d_in[1];
  const float* b1 = (const float*)d_in[2];
  const float* w2 = (const float*)d_in[3];
  const float* b2 = (const float*)d_in[4];
  float* out = (float*)d_out;
  double* parts = (double*)d_ws;  // 96*44*2 doubles = 67584 B

  dim3 grid(11, 96);
  sobel_pool_stats<<<grid, 256, 0, stream>>>(x, parts);
  stats_mlp<<<32, 256, 0, stream>>>(parts, w1, b1, w2, b2, out);
}

// Round 17
// 32.958 us; speedup vs baseline: 1.0518x; 1.0518x over previous
//
#include <hip/hip_runtime.h>
#include <math.h>

// x: [32,3,512,512] f32.
// Stage 1: shuffle-free 12-col-window row sweep — DS-latency probe.
// r15 (best, 30.2us) has 6 ds_bpermute/step serially in the dep chain;
// this variant eliminates ALL cross-lane ops: each lane loads cols
// c0-2..c0+9 (float2+float4+float4+float2, aligned; halo is L1-hit),
// computes Sobel mag for 10 cols, pools 8 — fully lane-local.
// vs r6 (57us, same window): builtin v_sqrt_f32 (not IEEE sqrtf),
// pair-sum ring, M-ring without copies, single code path (r16 showed
// template duplication thrashes I-cache).
// 12 output rows/wave, 44 chunks/(b,c) (43 real + 1 dummy), 4224 waves.
// Stage 2: 32 blocks (one per b), wave-per-channel double2 reduce + MLP.
// Grid: (11, 96) x 256  +  (32) x 256.

__global__ __launch_bounds__(256) void sobel_pool_stats(
    const float* __restrict__ x, double* __restrict__ parts) {
  const int tid = threadIdx.x;
  const int lane = tid & 63;
  const int w = tid >> 6;
  const int bc = blockIdx.y;                 // 0..95
  const int chunk = blockIdx.x * 4 + w;      // 0..43 (43 = dummy)
  const int row0 = chunk * 12;

  const float* __restrict__ xb = x + (size_t)bc * (512 * 512);
  const int c0 = lane * 8;                       // 8 output cols per lane
  const int offL = (lane > 0) ? c0 - 2 : 0;      // 8B-aligned
  const int offR = (lane < 63) ? c0 + 8 : 504;   // 8B-aligned
  const float lm = (lane > 0) ? 1.f : 0.f;
  const float rm = (lane < 63) ? 1.f : 0.f;

  // load x[r][c0-2 .. c0+9]; zeros outside the image
  auto load12 = [&](int r, float* o) {
    if ((unsigned)r < 512u) {                // wave-uniform branch
      const float* p = xb + (size_t)r * 512;
      float2 L = *(const float2*)(p + offL);
      float4 u = *(const float4*)(p + c0);
      float4 v = *(const float4*)(p + c0 + 4);
      float2 R = *(const float2*)(p + offR);
      o[0] = L.x * lm; o[1] = L.y * lm;
      o[2] = u.x; o[3] = u.y; o[4] = u.z; o[5] = u.w;
      o[6] = v.x; o[7] = v.y; o[8] = v.z; o[9] = v.w;
      o[10] = R.x * rm; o[11] = R.y * rm;
    } else {
#pragma unroll
      for (int k = 0; k < 12; ++k) o[k] = 0.f;
    }
  };

  float xprev[12], Po[12];   // pair-sum ring: Po = x[r-1]+x[r]
  float M[3][10];            // mag ring (compile-time %3 under full unroll)

  {
    float t0[12];
    load12(row0 - 2, t0);
    load12(row0 - 1, xprev);
#pragma unroll
    for (int k = 0; k < 12; ++k) Po[k] = t0[k] + xprev[k];
  }

  float s = 0.f, ss = 0.f;

#pragma unroll
  for (int t = 0; t < 14; ++t) {
    float xn[12], Pn[12];
    load12(row0 + t, xn);
#pragma unroll
    for (int k = 0; k < 12; ++k) Pn[k] = xprev[k] + xn[k];

    const int mrow = row0 + t - 1;            // mag row this step emits
    float* mg = M[t % 3];
    if ((unsigned)mrow < 512u) {              // wave-uniform
      float a[12], b[12];
#pragma unroll
      for (int k = 0; k < 12; ++k) { a[k] = Po[k] + Pn[k]; b[k] = Po[k] - Pn[k]; }
#pragma unroll
      for (int k = 0; k < 10; ++k) {
        float gx = a[k] - a[k + 2];                       // horiz [1,0,-1]
        float gy = fmaf(2.f, b[k + 1], b[k] + b[k + 2]);  // horiz [1,2,1]
        float m2 = fmaf(gx, gx, 1e-6f);
        m2 = fmaf(gy, gy, m2);
        mg[k] = __builtin_amdgcn_sqrtf(m2);
      }
      mg[0] *= lm;    // image col -1 -> 0 (lane 0 only)
      mg[9] *= rm;    // image col 512 -> 0 (lane 63 only)
    } else {
#pragma unroll
      for (int k = 0; k < 10; ++k) mg[k] = 0.f;
    }

    if (t >= 2) {
      if ((unsigned)(row0 + t - 2) < 512u) {  // pool row valid (wave-uniform)
        float* m0 = M[(t - 2) % 3];
        float* m1 = M[(t - 1) % 3];
        float cs[10];
#pragma unroll
        for (int k = 0; k < 10; ++k) cs[k] = (m0[k] + mg[k]) + m1[k];
#pragma unroll
        for (int j = 0; j < 8; ++j) {
          float tt = (cs[j] + cs[j + 2]) + cs[j + 1];
          s += tt;
          ss = fmaf(tt, tt, ss);
        }
      }
    }
#pragma unroll
    for (int k = 0; k < 12; ++k) { xprev[k] = xn[k]; Po[k] = Pn[k]; }
  }

  // per-wave double reduction; fold deferred /9, /81
  double ds = (double)s * (1.0 / 9.0);
  double dss = (double)ss * (1.0 / 81.0);
  for (int off = 32; off > 0; off >>= 1) {
    ds += __shfl_down(ds, off);
    dss += __shfl_down(dss, off);
  }
  if (lane == 0) {
    size_t idx = ((size_t)bc * 44 + chunk) * 2;
    parts[idx] = ds;
    parts[idx + 1] = dss;
  }
}

// One block per batch image b: waves 0-2 reduce channel 0-2's 44 double2
// partials lane-parallel, then feats [m0,s0,m1,s1,m2,s2] -> MLP -> out.
__global__ __launch_bounds__(256) void stats_mlp(
    const double* __restrict__ parts,
    const float* __restrict__ w1, const float* __restrict__ b1,
    const float* __restrict__ w2, const float* __restrict__ b2,
    float* __restrict__ out) {
  __shared__ float feats[6];
  __shared__ float hbuf[32];
  const int tid = threadIdx.x;
  const int lane = tid & 63;
  const int w = tid >> 6;
  const int b = blockIdx.x;                  // 0..31

  if (w < 3) {
    const int bc = b * 3 + w;
    const double2* p2 = (const double2*)(parts + (size_t)bc * 88);
    double s = 0.0, ss = 0.0;
    if (lane < 44) {
      double2 v = p2[lane];
      s = v.x;
      ss = v.y;
    }
    for (int off = 32; off > 0; off >>= 1) {
      s += __shfl_down(s, off);
      ss += __shfl_down(ss, off);
    }
    if (lane == 0) {
      const double N = 262144.0;
      double mean = s / N;
      double var = (ss - s * s / N) / (N - 1.0);
      if (var < 0.0) var = 0.0;
      feats[2 * w] = (float)mean;
      feats[2 * w + 1] = (float)sqrt(var);
    }
  }
  __syncthreads();

  if (tid < 32) {
    float acc = b1[tid];
#pragma unroll
    for (int k = 0; k < 6; ++k) acc += feats[k] * w1[tid * 6 + k];
    hbuf[tid] = acc > 0.f ? acc : 0.f;
  }
  __syncthreads();

  if (tid < 64) {
    float acc = b2[tid];
#pragma unroll
    for (int j = 0; j < 32; ++j) acc += hbuf[j] * w2[tid * 32 + j];
    out[(size_t)b * 64 + tid] = acc;
  }
}

extern "C" void kernel_launch(void* const* d_in, const int* in_sizes, int n_in,
                              void* d_out, int out_size, void* d_ws, size_t ws_size,
                              hipStream_t stream) {
  const float* x = (const float*)d_in[0];
  const float* w1 = (const float*)d_in[1];
  const float* b1 = (const float*)d_in[2];
  const float* w2 = (const float*)d_in[3];
  const float* b2 = (const float*)d_in[4];
  float* out = (float*)d_out;
  double* parts = (double*)d_ws;  // 96*44*2 doubles = 67584 B

  dim3 grid(11, 96);
  sobel_pool_stats<<<grid, 256, 0, stream>>>(x, parts);
  stats_mlp<<<32, 256, 0, stream>>>(parts, w1, b1, w2, b2, out);
}

// Round 18
// 32.258 us; speedup vs baseline: 1.0746x; 1.0217x over previous
//
#include <hip/hip_runtime.h>
#include <math.h>

// x: [32,3,512,512] f32.
// Stage 1 = r15's proven structure (best, 30.2us wall) with elementwise
// arithmetic rewritten as float2 ext-vectors to trigger CDNA packed-FP32
// VALU (v_pk_add_f32 / v_pk_fma_f32, 2 floats/instr, gfx90a+).
// Structure unchanged: 8 cols/lane (4 v2f pairs), 2 aligned float4
// loads/row, Sobel via rolling vertical pair-sums, 4 shuffles/mag row +
// 2/pool row (edge scalars extracted from pairs), builtin v_sqrt_f32,
// 12 output rows/wave, 44 chunks/(b,c) (43 real + 1 dummy), 4224 waves.
// Stage 2: 32 blocks (one per b), wave-per-channel double2 reduce + MLP.
// Grid: (11, 96) x 256  +  (32) x 256.

typedef float v2f __attribute__((ext_vector_type(2)));

static __device__ __forceinline__ v2f mkv2(float a, float b) {
  v2f r; r.x = a; r.y = b; return r;
}

__global__ __launch_bounds__(256) void sobel_pool_stats(
    const float* __restrict__ x, double* __restrict__ parts) {
  const int tid = threadIdx.x;
  const int lane = tid & 63;
  const int w = tid >> 6;
  const int bc = blockIdx.y;                 // 0..95
  const int chunk = blockIdx.x * 4 + w;      // 0..43 (43 = dummy)
  const int row0 = chunk * 12;

  const float* __restrict__ xb = x + (size_t)bc * (512 * 512) + lane * 8;

  auto load8 = [&](int r, v2f* o) {
    if ((unsigned)r < 512u) {                // wave-uniform branch
      const float* p = xb + (size_t)r * 512;
      float4 u = *(const float4*)(p);
      float4 v = *(const float4*)(p + 4);
      o[0] = mkv2(u.x, u.y); o[1] = mkv2(u.z, u.w);
      o[2] = mkv2(v.x, v.y); o[3] = mkv2(v.z, v.w);
    } else {
#pragma unroll
      for (int k = 0; k < 4; ++k) o[k] = mkv2(0.f, 0.f);
    }
  };

  v2f S[4], X[4];
  {
    v2f t0[4], t1[4];
    load8(row0 - 2, t0);
    load8(row0 - 1, t1);
#pragma unroll
    for (int k = 0; k < 4; ++k) { S[k] = t0[k] + t1[k]; X[k] = t1[k]; }
  }

  // Emit mag row rm (consumes x[rm+1]); advances S,X. mg=0 if rm OOB.
  auto magstep = [&](int rm, v2f* mg) {
    v2f xn[4], S2[4], A[4], B[4];
    load8(rm + 1, xn);
#pragma unroll
    for (int k = 0; k < 4; ++k) S2[k] = X[k] + xn[k];
#pragma unroll
    for (int k = 0; k < 4; ++k) { A[k] = S[k] + S2[k]; B[k] = S[k] - S2[k]; }
    float aL = __shfl_up(A[3].y, 1), aR = __shfl_down(A[0].x, 1);
    float bL = __shfl_up(B[3].y, 1), bR = __shfl_down(B[0].x, 1);
    if (lane == 0)  { aL = 0.f; bL = 0.f; }   // image col -1 = 0
    if (lane == 63) { aR = 0.f; bR = 0.f; }   // image col 512 = 0
    const float rmask = ((unsigned)rm < 512u) ? 1.f : 0.f;
    const v2f vmask = mkv2(rmask, rmask);
    const v2f eps = mkv2(1e-6f, 1e-6f);
#pragma unroll
    for (int p = 0; p < 4; ++p) {
      // shifted pairs: am = (a[2p-1], a[2p]),  ap = (a[2p+1], a[2p+2])
      v2f am = (p == 0) ? mkv2(aL, A[0].x) : mkv2(A[p - 1].y, A[p].x);
      v2f ap = (p == 3) ? mkv2(A[3].y, aR) : mkv2(A[p].y, A[p + 1].x);
      v2f bm = (p == 0) ? mkv2(bL, B[0].x) : mkv2(B[p - 1].y, B[p].x);
      v2f bp = (p == 3) ? mkv2(B[3].y, bR) : mkv2(B[p].y, B[p + 1].x);
      v2f gx = am - ap;                        // horiz [1,0,-1]
      v2f gy = B[p] * 2.f + (bm + bp);         // horiz [1,2,1] (pk_fma)
      v2f m2 = gx * gx + eps;                  // pk_fma
      m2 = gy * gy + m2;                       // pk_fma
      v2f r;
      r.x = __builtin_amdgcn_sqrtf(m2.x);
      r.y = __builtin_amdgcn_sqrtf(m2.y);
      mg[p] = r * vmask;
    }
#pragma unroll
    for (int k = 0; k < 4; ++k) { S[k] = S2[k]; X[k] = xn[k]; }
  };

  v2f MM[4], MC[4], MP[4];
  magstep(row0 - 1, MM);
  magstep(row0, MC);

  v2f sacc = mkv2(0.f, 0.f), ssacc = mkv2(0.f, 0.f);
#pragma unroll
  for (int i = 0; i < 12; ++i) {
    magstep(row0 + 1 + i, MP);               // mag[r+1]
    {                                        // all 12 output rows real
      v2f cs[4];
#pragma unroll
      for (int k = 0; k < 4; ++k) cs[k] = (MM[k] + MP[k]) + MC[k];
      float csL = __shfl_up(cs[3].y, 1), csR = __shfl_down(cs[0].x, 1);
      if (lane == 0) csL = 0.f;
      if (lane == 63) csR = 0.f;
#pragma unroll
      for (int p = 0; p < 4; ++p) {
        v2f cm = (p == 0) ? mkv2(csL, cs[0].x) : mkv2(cs[p - 1].y, cs[p].x);
        v2f cp = (p == 3) ? mkv2(cs[3].y, csR) : mkv2(cs[p].y, cs[p + 1].x);
        v2f t = (cm + cp) + cs[p];
        sacc = sacc + t;
        ssacc = t * t + ssacc;               // pk_fma
      }
    }
#pragma unroll
    for (int k = 0; k < 4; ++k) { MM[k] = MC[k]; MC[k] = MP[k]; }
  }

  float s = sacc.x + sacc.y;
  float ssv = ssacc.x + ssacc.y;

  // per-wave double reduction; fold deferred /9, /81
  double ds = (double)s * (1.0 / 9.0);
  double dss = (double)ssv * (1.0 / 81.0);
  for (int off = 32; off > 0; off >>= 1) {
    ds += __shfl_down(ds, off);
    dss += __shfl_down(dss, off);
  }
  if (lane == 0) {
    size_t idx = ((size_t)bc * 44 + chunk) * 2;
    parts[idx] = ds;
    parts[idx + 1] = dss;
  }
}

// One block per batch image b: waves 0-2 reduce channel 0-2's 44 double2
// partials lane-parallel, then feats [m0,s0,m1,s1,m2,s2] -> MLP -> out.
__global__ __launch_bounds__(256) void stats_mlp(
    const double* __restrict__ parts,
    const float* __restrict__ w1, const float* __restrict__ b1,
    const float* __restrict__ w2, const float* __restrict__ b2,
    float* __restrict__ out) {
  __shared__ float feats[6];
  __shared__ float hbuf[32];
  const int tid = threadIdx.x;
  const int lane = tid & 63;
  const int w = tid >> 6;
  const int b = blockIdx.x;                  // 0..31

  if (w < 3) {
    const int bc = b * 3 + w;
    const double2* p2 = (const double2*)(parts + (size_t)bc * 88);
    double s = 0.0, ss = 0.0;
    if (lane < 44) {
      double2 v = p2[lane];
      s = v.x;
      ss = v.y;
    }
    for (int off = 32; off > 0; off >>= 1) {
      s += __shfl_down(s, off);
      ss += __shfl_down(ss, off);
    }
    if (lane == 0) {
      const double N = 262144.0;
      double mean = s / N;
      double var = (ss - s * s / N) / (N - 1.0);
      if (var < 0.0) var = 0.0;
      feats[2 * w] = (float)mean;
      feats[2 * w + 1] = (float)sqrt(var);
    }
  }
  __syncthreads();

  if (tid < 32) {
    float acc = b1[tid];
#pragma unroll
    for (int k = 0; k < 6; ++k) acc += feats[k] * w1[tid * 6 + k];
    hbuf[tid] = acc > 0.f ? acc : 0.f;
  }
  __syncthreads();

  if (tid < 64) {
    float acc = b2[tid];
#pragma unroll
    for (int j = 0; j < 32; ++j) acc += hbuf[j] * w2[tid * 32 + j];
    out[(size_t)b * 64 + tid] = acc;
  }
}

extern "C" void kernel_launch(void* const* d_in, const int* in_sizes, int n_in,
                              void* d_out, int out_size, void* d_ws, size_t ws_size,
                              hipStream_t stream) {
  const float* x = (const float*)d_in[0];
  const float* w1 = (const float*)d_in[1];
  const float* b1 = (const float*)d_in[2];
  const float* w2 = (const float*)d_in[3];
  const float* b2 = (const float*)d_in[4];
  float* out = (float*)d_out;
  double* parts = (double*)d_ws;  // 96*44*2 doubles = 67584 B

  dim3 grid(11, 96);
  sobel_pool_stats<<<grid, 256, 0, stream>>>(x, parts);
  stats_mlp<<<32, 256, 0, stream>>>(parts, w1, b1, w2, b2, out);
}